// Round 9
// baseline (78.785 us; speedup 1.0000x reference)
//
#include <hip/hip_runtime.h>
#include <stdint.h>

#define B_ 16
#define N_ 4096
#define C_ 64
#define BN_ 65536

__device__ __forceinline__ float clipf(float x, float lo, float hi) {
    return fminf(fmaxf(x, lo), hi);
}
__device__ __forceinline__ float bcastf(float v, int l) {
    return __int_as_float(__builtin_amdgcn_readlane(__float_as_int(v), l));
}
__device__ __forceinline__ unsigned long long bcast64(unsigned long long v, int l) {
    unsigned int lo = (unsigned int)__builtin_amdgcn_readlane((int)(unsigned int)v, l);
    unsigned int hi = (unsigned int)__builtin_amdgcn_readlane((int)(unsigned int)(v >> 32), l);
    return ((unsigned long long)hi << 32) | lo;
}
// IoU with reference-exact rounding (no FMA contraction).
__device__ __forceinline__ float iou_rn(
    float ax1, float ay1, float ax2, float ay2, float aar,
    float bx1, float by1, float bx2, float by2, float bar)
{
    float ltx = fmaxf(ax1, bx1), lty = fmaxf(ay1, by1);
    float rbx = fminf(ax2, bx2), rby = fminf(ay2, by2);
    float wx  = fmaxf(__fsub_rn(rbx, ltx), 0.f);
    float wy  = fmaxf(__fsub_rn(rby, lty), 0.f);
    float inter = __fmul_rn(wx, wy);
    float uni   = __fsub_rn(__fadd_rn(aar, bar), inter);
    return inter / __fadd_rn(uni, 1e-7f);
}
// clip exactly as the reference (fminf/fmaxf deterministic, bit-exact)
__device__ __forceinline__ float4 load_clip(const float* __restrict__ proposals,
                                            int src)
{
    float4 bx = *reinterpret_cast<const float4*>(proposals + (size_t)src * 4);
    return make_float4(clipf(bx.x, 0.f, 602.f), clipf(bx.y, 0.f, 602.f),
                       clipf(bx.z, 0.f, 602.f), clipf(bx.w, 0.f, 602.f));
}

// ---------------------------------------------------------------------------
// Kernel 1: per-box score/cls/valid + 32-bit sort key + zero the output.
// (byte-identical logic to round-7/8 passing version)
// ---------------------------------------------------------------------------
__global__ __launch_bounds__(256) void score_kernel(
    const float* __restrict__ proposals,      // [B,N,4]
    const float* __restrict__ preds,          // [B,N,C]
    const float* __restrict__ scores,         // [B,N]
    unsigned int* __restrict__ key32,         // [B,N]
    float* __restrict__ conf_o,               // [B,N]
    float* __restrict__ clsf_o,               // [B,N]
    unsigned char* __restrict__ cv_o,         // [B,N] valid?cls:255
    float* __restrict__ out)                  // [B,N,7] zero-fill
{
    const int gt  = blockIdx.x * 256 + threadIdx.x;   // BN*16 threads
    if (gt < BN_ * 7) out[gt] = 0.f;                  // deterministic zero-init
    const int wid = gt >> 4;
    const int sub = gt & 15;

    float obj = scores[wid];
    float4 p4 = *reinterpret_cast<const float4*>(preds + (size_t)wid * C_ + sub * 4);
    float v; int idx;
    {
        float v0 = p4.x * obj, v1 = p4.y * obj, v2 = p4.z * obj, v3 = p4.w * obj;
        v = v0; idx = sub * 4;                      // strict > keeps lowest idx
        if (v1 > v) { v = v1; idx = sub * 4 + 1; }
        if (v2 > v) { v = v2; idx = sub * 4 + 2; }
        if (v3 > v) { v = v3; idx = sub * 4 + 3; }
    }
    #pragma unroll
    for (int o = 8; o > 0; o >>= 1) {   // 16-lane aligned groups within wave
        float vv = __shfl_xor(v, o, 64);
        int   ii = __shfl_xor(idx, o, 64);
        if (vv > v || (vv == v && ii < idx)) { v = vv; idx = ii; }
    }

    if (sub == 0) {
        float4 bx = *reinterpret_cast<const float4*>(proposals + (size_t)wid * 4);
        float x1 = clipf(bx.x, 0.f, 602.f);
        float y1 = clipf(bx.y, 0.f, 602.f);
        float x2 = clipf(bx.z, 0.f, 602.f);
        float y2 = clipf(bx.w, 0.f, 602.f);
        bool valid = (obj > 0.01f) && ((x2 - x1) >= 5.f) && ((y2 - y1) >= 5.f)
                     && (v > 0.001f);
        float keyf = valid ? v : -1e9f;
        unsigned int u = __float_as_uint(keyf);
        u ^= (u >> 31) ? 0xFFFFFFFFu : 0x80000000u;
        key32[wid] = ~u;                               // ascending == conf DESC
        conf_o[wid] = v;
        clsf_o[wid] = (float)idx;
        cv_o[wid]   = valid ? (unsigned char)idx : (unsigned char)255;
    }
}

#define CE_(A, Bq)                                                              \
        {                                                                       \
            bool sw = (kr[A] > kr[Bq]) || (kr[A] == kr[Bq] && pr[A] > pr[Bq]);  \
            if (sw) {                                                           \
                unsigned int tk = kr[A]; kr[A] = kr[Bq]; kr[Bq] = tk;           \
                unsigned short tp = pr[A]; pr[A] = pr[Bq]; pr[Bq] = tp;         \
            }                                                                   \
        }

// ---------------------------------------------------------------------------
// Kernel 2: 128 blocks; each stably sorts a 512-element run (LDS merge).
// (byte-identical to round-4/5 passing version)
// ---------------------------------------------------------------------------
__global__ __launch_bounds__(128) void sortA_kernel(
    const unsigned int* __restrict__ key32,
    unsigned int* __restrict__ runkey,
    unsigned short* __restrict__ runpay)
{
    __shared__ unsigned int  k0[512], k1[512];
    __shared__ unsigned short p0[512], p1[512];
    const int blk = blockIdx.x;
    const int b = blk >> 3, c = blk & 7;
    const int t = threadIdx.x;               // 0..127
    const int g0 = b * N_ + c * 512;

    {
        uint4 kk = *reinterpret_cast<const uint4*>(key32 + g0 + t * 4);
        unsigned int  kr[4] = {kk.x, kk.y, kk.z, kk.w};
        unsigned short pr[4] = {(unsigned short)(c * 512 + t * 4),
                                (unsigned short)(c * 512 + t * 4 + 1),
                                (unsigned short)(c * 512 + t * 4 + 2),
                                (unsigned short)(c * 512 + t * 4 + 3)};
        CE_(0, 1) CE_(2, 3) CE_(0, 2) CE_(1, 3) CE_(1, 2)
        #pragma unroll
        for (int s = 0; s < 4; ++s) { k0[t * 4 + s] = kr[s]; p0[t * 4 + s] = pr[s]; }
    }

    unsigned int*  ks = k0; unsigned int*  kd = k1;
    unsigned short* ps = p0; unsigned short* pd = p1;

    for (int dlog = 2; dlog <= 8; ++dlog) {        // runs 4 -> 512
        const int R = 1 << dlog;
        __syncthreads();
        unsigned int  mk[4]; unsigned short mp[4];
        int lo[4], hi[4], sb[4], db[4]; bool teq[4];
        #pragma unroll
        for (int s = 0; s < 4; ++s) {
            int i = t + s * 128;
            mk[s] = ks[i]; mp[s] = ps[i];
            int base = i & ~(2 * R - 1);
            bool isA = (i & R) == 0;
            sb[s] = base + (isA ? R : 0);
            db[s] = base + (i & (R - 1));
            teq[s] = !isA;                 // B counts equal-A as less (upper_bound)
            lo[s] = -1; hi[s] = R;
        }
        for (int it = 0; it < dlog + 1; ++it) {    // lockstep ILP-4
            #pragma unroll
            for (int s = 0; s < 4; ++s) {
                if (hi[s] - lo[s] > 1) {
                    int mid = (lo[s] + hi[s]) >> 1;
                    unsigned int sk = ks[sb[s] + mid];
                    bool less = (sk < mk[s]) || (sk == mk[s] && teq[s]);
                    if (less) lo[s] = mid; else hi[s] = mid;
                }
            }
        }
        #pragma unroll
        for (int s = 0; s < 4; ++s) {
            kd[db[s] + hi[s]] = mk[s];
            pd[db[s] + hi[s]] = mp[s];
        }
        unsigned int*  tk = ks; ks = kd; kd = tk;
        unsigned short* tp = ps; ps = pd; pd = tp;
    }
    __syncthreads();
    #pragma unroll
    for (int s = 0; s < 4; ++s) {
        int i = t + s * 128;
        runkey[g0 + i] = ks[i];
        runpay[g0 + i] = ps[i];
    }
}

// ---------------------------------------------------------------------------
// Kernel 3: 8-way stable RANK (8x512 -> 4096 sorted positions), writing only
// perm[dst] = within-batch source index and cv_s[dst].  Element in run ri at
// in-run pos p lands at p + sum_{j!=ri} cnt_j; cnt_j = upper_bound for j<ri,
// lower_bound for j>ri (runs = contiguous original-index ranges -> stable ==
// reference argsort ties).  All arrays static-indexed (rule #20): the own-run
// search runs too (harmless) and is excluded by a compile-time-j select.
// ---------------------------------------------------------------------------
__global__ __launch_bounds__(256) void rank8_kernel(
    const unsigned int* __restrict__ runkey,
    const unsigned short* __restrict__ runpay,
    const unsigned char* __restrict__ cv,
    unsigned short* __restrict__ perm,
    unsigned char* __restrict__ cv_s)
{
    const int i = blockIdx.x * 256 + threadIdx.x;   // BN threads
    const int batch = i >> 12;
    const int run   = (i >> 9) & 7;
    const int p     = i & 511;
    const unsigned int mk = runkey[i];
    const unsigned short mp = runpay[i];
    const unsigned int* kb = runkey + (batch << 12);

    int lo[8], hi[8];
    #pragma unroll
    for (int j = 0; j < 8; ++j) { lo[j] = -1; hi[j] = 512; }
    for (int it = 0; it < 10; ++it) {               // lockstep ILP-8
        #pragma unroll
        for (int j = 0; j < 8; ++j) {
            if (hi[j] - lo[j] > 1) {
                int mid = (lo[j] + hi[j]) >> 1;
                unsigned int sk = kb[(j << 9) + mid];
                bool less = (sk < mk) || (sk == mk && (j < run));
                if (less) lo[j] = mid; else hi[j] = mid;
            }
        }
    }
    int dst = (batch << 12) + p;
    #pragma unroll
    for (int j = 0; j < 8; ++j) dst += (j == run) ? 0 : hi[j];

    perm[dst] = mp;
    cv_s[dst] = cv[(batch << 12) + (int)mp];
}

// ---------------------------------------------------------------------------
// Kernel 4: per-(batch,class) greedy NMS, one wave/block; boxes re-derived
// from proposals via perm with reference-exact clip; writes survivors' rows
// directly (out pre-zeroed by score_kernel).  NMS math byte-identical to the
// round-7/8 passing version.
// ---------------------------------------------------------------------------
__device__ __forceinline__ void emit_row(
    const float* __restrict__ proposals, const float* __restrict__ conf,
    const float* __restrict__ clsf, const unsigned short* __restrict__ perm,
    float* __restrict__ out, int row)
{
    int src = (row & ~(N_ - 1)) | (int)perm[row];
    float4 bb = load_clip(proposals, src);
    size_t o = (size_t)row * 6;
    out[o + 0] = bb.x; out[o + 1] = bb.y;
    out[o + 2] = bb.z; out[o + 3] = bb.w;
    out[o + 4] = conf[src];
    out[o + 5] = clsf[src];
    out[(size_t)BN_ * 6 + row] = 1.f;
}

__global__ __launch_bounds__(64) void nms_kernel(
    const float* __restrict__ proposals,
    const float* __restrict__ conf,
    const float* __restrict__ clsf,
    const unsigned char* __restrict__ cv_s,
    const unsigned short* __restrict__ perm,
    float* __restrict__ out)
{
    __shared__ unsigned short flist[N_];
    __shared__ unsigned char alive8[N_];
    const int bc = blockIdx.x;
    const int b = bc >> 6, c = bc & 63;
    const int lane = threadIdx.x;
    const float offc = (float)c * 4096.0f;          // exact in f32
    const unsigned char* cv = cv_s + (size_t)b * N_;
    const unsigned short* pm = perm + (size_t)b * N_;

    // ordered ballot compaction (single wave; LDS program-ordered)
    int base = 0;
    #pragma unroll 16
    for (int it = 0; it < N_ / 64; ++it) {
        bool pred = cv[it * 64 + lane] == (unsigned char)c;
        unsigned long long m = __ballot(pred);
        if (pred)
            flist[base + __popcll(m & ((1ull << lane) - 1ull))] =
                (unsigned short)(it * 64 + lane);
        base += __popcll(m);
    }
    const int L = base;
    if (L <= 1) {
        if (lane < L)
            emit_row(proposals, conf, clsf, perm, out, b * N_ + flist[lane]);
        return;
    }

    if (L <= 64) {
        bool in = lane < L;
        unsigned short myp = in ? flist[lane] : (unsigned short)0;
        float x1 = offc, y1 = offc, x2 = offc, y2 = offc, ar = 0.f;
        if (in) {
            int src = (b << 12) + (int)pm[myp];
            float4 bb = load_clip(proposals, src);
            x1 = __fadd_rn(bb.x, offc); y1 = __fadd_rn(bb.y, offc);
            x2 = __fadd_rn(bb.z, offc); y2 = __fadd_rn(bb.w, offc);
            ar = __fmul_rn(fmaxf(__fsub_rn(x2, x1), 0.f),
                           fmaxf(__fsub_rn(y2, y1), 0.f));
        }
        // parallel suppression bit-matrix: no loop-carried dependency
        unsigned long long row = 0;
        for (int j = 1; j < L; ++j) {
            float jx1 = bcastf(x1, j), jy1 = bcastf(y1, j);
            float jx2 = bcastf(x2, j), jy2 = bcastf(y2, j);
            float jar = bcastf(ar, j);
            float iou = iou_rn(jx1, jy1, jx2, jy2, jar, x1, y1, x2, y2, ar);
            if (in && j > lane && iou > 0.2f) row |= 1ull << j;
        }
        // serial cascade over bits
        unsigned long long alive = (L >= 64) ? ~0ull : ((1ull << L) - 1ull);
        unsigned int rlo = (unsigned int)row, rhi = (unsigned int)(row >> 32);
        for (int k = 0; k < L - 1; ++k) {
            if ((alive >> k) & 1ull) {
                unsigned int lo = (unsigned int)__builtin_amdgcn_readlane((int)rlo, k);
                unsigned int hi = (unsigned int)__builtin_amdgcn_readlane((int)rhi, k);
                alive &= ~(((unsigned long long)hi << 32) | (unsigned long long)lo);
            }
        }
        if (in && ((alive >> lane) & 1ull))
            emit_row(proposals, conf, clsf, perm, out, b * N_ + myp);
    } else if (L <= 128) {
        bool in1 = (64 + lane) < L;
        unsigned short myp0 = flist[lane];
        unsigned short myp1 = in1 ? flist[64 + lane] : (unsigned short)0;
        float ax1, ay1, ax2, ay2, aar;
        {
            int src = (b << 12) + (int)pm[myp0];
            float4 bb = load_clip(proposals, src);
            ax1 = __fadd_rn(bb.x, offc); ay1 = __fadd_rn(bb.y, offc);
            ax2 = __fadd_rn(bb.z, offc); ay2 = __fadd_rn(bb.w, offc);
            aar = __fmul_rn(fmaxf(__fsub_rn(ax2, ax1), 0.f),
                            fmaxf(__fsub_rn(ay2, ay1), 0.f));
        }
        float bx1 = offc, by1 = offc, bx2 = offc, by2 = offc, bar = 0.f;
        if (in1) {
            int src = (b << 12) + (int)pm[myp1];
            float4 bb = load_clip(proposals, src);
            bx1 = __fadd_rn(bb.x, offc); by1 = __fadd_rn(bb.y, offc);
            bx2 = __fadd_rn(bb.z, offc); by2 = __fadd_rn(bb.w, offc);
            bar = __fmul_rn(fmaxf(__fsub_rn(bx2, bx1), 0.f),
                            fmaxf(__fsub_rn(by2, by1), 0.f));
        }
        unsigned long long r0lo = 0, r0hi = 0, r1hi = 0;
        for (int j = 1; j < 64; ++j) {
            float jx1 = bcastf(ax1, j), jy1 = bcastf(ay1, j);
            float jx2 = bcastf(ax2, j), jy2 = bcastf(ay2, j);
            float jar = bcastf(aar, j);
            float i0 = iou_rn(jx1, jy1, jx2, jy2, jar, ax1, ay1, ax2, ay2, aar);
            if (j > lane && i0 > 0.2f) r0lo |= 1ull << j;
        }
        const int Lh = L - 64;
        for (int jm = 0; jm < Lh; ++jm) {
            float jx1 = bcastf(bx1, jm), jy1 = bcastf(by1, jm);
            float jx2 = bcastf(bx2, jm), jy2 = bcastf(by2, jm);
            float jar = bcastf(bar, jm);
            float i0 = iou_rn(jx1, jy1, jx2, jy2, jar, ax1, ay1, ax2, ay2, aar);
            if (i0 > 0.2f) r0hi |= 1ull << jm;      // 64+jm > lane always
            float i1 = iou_rn(jx1, jy1, jx2, jy2, jar, bx1, by1, bx2, by2, bar);
            if (in1 && jm > lane && i1 > 0.2f) r1hi |= 1ull << jm;
        }
        unsigned long long alo = ~0ull;
        unsigned long long ahi = (Lh >= 64) ? ~0ull : ((1ull << Lh) - 1ull);
        for (int k = 0; k < 64; ++k) {
            if ((alo >> k) & 1ull) {
                alo &= ~bcast64(r0lo, k);
                ahi &= ~bcast64(r0hi, k);
            }
        }
        for (int k = 0; k < Lh - 1; ++k) {
            if ((ahi >> k) & 1ull) ahi &= ~bcast64(r1hi, k);
        }
        if ((alo >> lane) & 1ull)
            emit_row(proposals, conf, clsf, perm, out, b * N_ + myp0);
        if (in1 && ((ahi >> lane) & 1ull))
            emit_row(proposals, conf, clsf, perm, out, b * N_ + myp1);
    } else {
        // generic fallback (not expected with this data)
        for (int j = lane; j < L; j += 64) alive8[j] = 1;
        for (int k = 0; k < L - 1; ++k) {
            if (!alive8[k]) continue;
            int ksrc = (b << 12) + (int)pm[flist[k]];
            float4 kb = load_clip(proposals, ksrc);
            float kx1 = __fadd_rn(kb.x, offc), ky1 = __fadd_rn(kb.y, offc);
            float kx2 = __fadd_rn(kb.z, offc), ky2 = __fadd_rn(kb.w, offc);
            float kar = __fmul_rn(fmaxf(__fsub_rn(kx2, kx1), 0.f),
                                  fmaxf(__fsub_rn(ky2, ky1), 0.f));
            for (int j = k + 1 + lane; j < L; j += 64) {
                if (!alive8[j]) continue;
                int jsrc = (b << 12) + (int)pm[flist[j]];
                float4 bb = load_clip(proposals, jsrc);
                float a1 = __fadd_rn(bb.x, offc), b1 = __fadd_rn(bb.y, offc);
                float a2 = __fadd_rn(bb.z, offc), b2 = __fadd_rn(bb.w, offc);
                float arj = __fmul_rn(fmaxf(__fsub_rn(a2, a1), 0.f),
                                      fmaxf(__fsub_rn(b2, b1), 0.f));
                float iou = iou_rn(kx1, ky1, kx2, ky2, kar, a1, b1, a2, b2, arj);
                if (iou > 0.2f) alive8[j] = 0;
            }
        }
        for (int j = lane; j < L; j += 64)
            if (alive8[j])
                emit_row(proposals, conf, clsf, perm, out, b * N_ + flist[j]);
    }
}

// ---------------------------------------------------------------------------
extern "C" void kernel_launch(void* const* d_in, const int* in_sizes, int n_in,
                              void* d_out, int out_size, void* d_ws, size_t ws_size,
                              hipStream_t stream) {
    (void)in_sizes; (void)n_in; (void)out_size; (void)ws_size;
    const float* proposals = (const float*)d_in[0];
    const float* preds     = (const float*)d_in[1];
    const float* scores    = (const float*)d_in[2];
    float* out = (float*)d_out;

    uint8_t* w = (uint8_t*)d_ws;
    unsigned int* key32    = (unsigned int*)(w);                      // 0..4
    float* conf            = (float*)(w + (size_t)BN_ * 4);           // 4..8
    float* clsf            = (float*)(w + (size_t)BN_ * 8);           // 8..12
    unsigned int* runkey   = (unsigned int*)(w + (size_t)BN_ * 12);   // 12..16
    unsigned short* runpay = (unsigned short*)(w + (size_t)BN_ * 16); // 16..18
    unsigned short* perm   = (unsigned short*)(w + (size_t)BN_ * 18); // 18..20
    unsigned char* cv      = w + (size_t)BN_ * 20;                    // 20..21
    unsigned char* cv_s    = w + (size_t)BN_ * 21;                    // 21..22

    score_kernel<<<(BN_ * 16) / 256, 256, 0, stream>>>(
        proposals, preds, scores, key32, conf, clsf, cv, out);
    sortA_kernel<<<128, 128, 0, stream>>>(key32, runkey, runpay);
    rank8_kernel<<<BN_ / 256, 256, 0, stream>>>(
        runkey, runpay, cv, perm, cv_s);
    nms_kernel<<<B_ * C_, 64, 0, stream>>>(
        proposals, conf, clsf, cv_s, perm, out);
}

// Round 10
// 73.293 us; speedup vs baseline: 1.0749x; 1.0749x over previous
//
#include <hip/hip_runtime.h>
#include <stdint.h>

#define B_ 16
#define N_ 4096
#define C_ 64
#define BN_ 65536

__device__ __forceinline__ float clipf(float x, float lo, float hi) {
    return fminf(fmaxf(x, lo), hi);
}
__device__ __forceinline__ float bcastf(float v, int l) {
    return __int_as_float(__builtin_amdgcn_readlane(__float_as_int(v), l));
}
__device__ __forceinline__ unsigned long long bcast64(unsigned long long v, int l) {
    unsigned int lo = (unsigned int)__builtin_amdgcn_readlane((int)(unsigned int)v, l);
    unsigned int hi = (unsigned int)__builtin_amdgcn_readlane((int)(unsigned int)(v >> 32), l);
    return ((unsigned long long)hi << 32) | lo;
}
// IoU with reference-exact rounding (no FMA contraction).
__device__ __forceinline__ float iou_rn(
    float ax1, float ay1, float ax2, float ay2, float aar,
    float bx1, float by1, float bx2, float by2, float bar)
{
    float ltx = fmaxf(ax1, bx1), lty = fmaxf(ay1, by1);
    float rbx = fminf(ax2, bx2), rby = fminf(ay2, by2);
    float wx  = fmaxf(__fsub_rn(rbx, ltx), 0.f);
    float wy  = fmaxf(__fsub_rn(rby, lty), 0.f);
    float inter = __fmul_rn(wx, wy);
    float uni   = __fsub_rn(__fadd_rn(aar, bar), inter);
    return inter / __fadd_rn(uni, 1e-7f);
}

// ---------------------------------------------------------------------------
// Kernel 1: per-box score/cls/valid + 32-bit sort key + zero the output.
// ---------------------------------------------------------------------------
__global__ __launch_bounds__(256) void score_kernel(
    const float* __restrict__ proposals,      // [B,N,4]
    const float* __restrict__ preds,          // [B,N,C]
    const float* __restrict__ scores,         // [B,N]
    unsigned int* __restrict__ key32,         // [B,N]
    float* __restrict__ conf_o,               // [B,N]
    float* __restrict__ clsf_o,               // [B,N]
    unsigned char* __restrict__ cv_o,         // [B,N] valid?cls:255
    float* __restrict__ out)                  // [B,N,7] zero-fill
{
    const int gt  = blockIdx.x * 256 + threadIdx.x;   // BN*16 threads
    if (gt < BN_ * 7) out[gt] = 0.f;                  // deterministic zero-init
    const int wid = gt >> 4;
    const int sub = gt & 15;

    float obj = scores[wid];
    float4 p4 = *reinterpret_cast<const float4*>(preds + (size_t)wid * C_ + sub * 4);
    float v; int idx;
    {
        float v0 = p4.x * obj, v1 = p4.y * obj, v2 = p4.z * obj, v3 = p4.w * obj;
        v = v0; idx = sub * 4;                      // strict > keeps lowest idx
        if (v1 > v) { v = v1; idx = sub * 4 + 1; }
        if (v2 > v) { v = v2; idx = sub * 4 + 2; }
        if (v3 > v) { v = v3; idx = sub * 4 + 3; }
    }
    #pragma unroll
    for (int o = 8; o > 0; o >>= 1) {   // 16-lane aligned groups within wave
        float vv = __shfl_xor(v, o, 64);
        int   ii = __shfl_xor(idx, o, 64);
        if (vv > v || (vv == v && ii < idx)) { v = vv; idx = ii; }
    }

    if (sub == 0) {
        float4 bx = *reinterpret_cast<const float4*>(proposals + (size_t)wid * 4);
        float x1 = clipf(bx.x, 0.f, 602.f);
        float y1 = clipf(bx.y, 0.f, 602.f);
        float x2 = clipf(bx.z, 0.f, 602.f);
        float y2 = clipf(bx.w, 0.f, 602.f);
        bool valid = (obj > 0.01f) && ((x2 - x1) >= 5.f) && ((y2 - y1) >= 5.f)
                     && (v > 0.001f);
        float keyf = valid ? v : -1e9f;
        unsigned int u = __float_as_uint(keyf);
        u ^= (u >> 31) ? 0xFFFFFFFFu : 0x80000000u;
        key32[wid] = ~u;                               // ascending == conf DESC
        conf_o[wid] = v;
        clsf_o[wid] = (float)idx;
        cv_o[wid]   = valid ? (unsigned char)idx : (unsigned char)255;
    }
}

#define CE_(A, Bq)                                                              \
        {                                                                       \
            bool sw = (kr[A] > kr[Bq]) || (kr[A] == kr[Bq] && pr[A] > pr[Bq]);  \
            if (sw) {                                                           \
                unsigned int tk = kr[A]; kr[A] = kr[Bq]; kr[Bq] = tk;           \
                unsigned short tp = pr[A]; pr[A] = pr[Bq]; pr[Bq] = tp;         \
            }                                                                   \
        }

// ---------------------------------------------------------------------------
// Kernel 2: 64 blocks; each stably sorts a 1024-element run (LDS merge).
// ---------------------------------------------------------------------------
__global__ __launch_bounds__(256) void sortA_kernel(
    const unsigned int* __restrict__ key32,
    unsigned int* __restrict__ runkey,
    unsigned short* __restrict__ runpay)
{
    __shared__ unsigned int  k0[1024], k1[1024];
    __shared__ unsigned short p0[1024], p1[1024];
    const int r = blockIdx.x;                // run id: batch r>>2, quarter r&3
    const int t = threadIdx.x;               // 0..255
    const int g0 = r * 1024;

    {
        uint4 kk = *reinterpret_cast<const uint4*>(key32 + g0 + t * 4);
        unsigned int  kr[4] = {kk.x, kk.y, kk.z, kk.w};
        unsigned short pr[4] = {(unsigned short)((r & 3) * 1024 + t * 4),
                                (unsigned short)((r & 3) * 1024 + t * 4 + 1),
                                (unsigned short)((r & 3) * 1024 + t * 4 + 2),
                                (unsigned short)((r & 3) * 1024 + t * 4 + 3)};
        CE_(0, 1) CE_(2, 3) CE_(0, 2) CE_(1, 3) CE_(1, 2)
        #pragma unroll
        for (int s = 0; s < 4; ++s) { k0[t * 4 + s] = kr[s]; p0[t * 4 + s] = pr[s]; }
    }

    unsigned int*  ks = k0; unsigned int*  kd = k1;
    unsigned short* ps = p0; unsigned short* pd = p1;

    for (int dlog = 2; dlog <= 9; ++dlog) {        // runs 4 -> 1024
        const int R = 1 << dlog;
        __syncthreads();
        unsigned int  mk[4]; unsigned short mp[4];
        int lo[4], hi[4], sb[4], db[4]; bool teq[4];
        #pragma unroll
        for (int s = 0; s < 4; ++s) {
            int i = t + s * 256;
            mk[s] = ks[i]; mp[s] = ps[i];
            int base = i & ~(2 * R - 1);
            bool isA = (i & R) == 0;
            sb[s] = base + (isA ? R : 0);
            db[s] = base + (i & (R - 1));
            teq[s] = !isA;                 // B counts equal-A as less (upper_bound)
            lo[s] = -1; hi[s] = R;
        }
        for (int it = 0; it < dlog + 1; ++it) {    // lockstep ILP-4
            #pragma unroll
            for (int s = 0; s < 4; ++s) {
                if (hi[s] - lo[s] > 1) {
                    int mid = (lo[s] + hi[s]) >> 1;
                    unsigned int sk = ks[sb[s] + mid];
                    bool less = (sk < mk[s]) || (sk == mk[s] && teq[s]);
                    if (less) lo[s] = mid; else hi[s] = mid;
                }
            }
        }
        #pragma unroll
        for (int s = 0; s < 4; ++s) {
            kd[db[s] + hi[s]] = mk[s];
            pd[db[s] + hi[s]] = mp[s];
        }
        unsigned int*  tk = ks; ks = kd; kd = tk;
        unsigned short* tp = ps; ps = pd; pd = tp;
    }
    __syncthreads();
    #pragma unroll
    for (int s = 0; s < 4; ++s) {
        int i = t + s * 256;
        runkey[g0 + i] = ks[i];
        runpay[g0 + i] = ps[i];
    }
}

// ---------------------------------------------------------------------------
// Kernel 3: global merge round 1024 -> 2048, one element per thread.
// ---------------------------------------------------------------------------
__global__ __launch_bounds__(256) void merge1_kernel(
    const unsigned int* __restrict__ ksrc,
    const unsigned short* __restrict__ psrc,
    unsigned int* __restrict__ kdst,
    unsigned short* __restrict__ pdst)
{
    const int i = blockIdx.x * 256 + threadIdx.x;   // BN threads
    const int R = 1024;
    unsigned int mk = ksrc[i]; unsigned short mp = psrc[i];
    int base = i & ~(2 * R - 1);
    bool isA = (i & R) == 0;
    int sb = base + (isA ? R : 0);
    int db = base + (i & (R - 1));
    bool teq = !isA;
    int lo = -1, hi = R;
    for (int s = 0; s < 11; ++s) {
        if (hi - lo > 1) {
            int mid = (lo + hi) >> 1;
            unsigned int sk = ksrc[sb + mid];
            bool less = (sk < mk) || (sk == mk && teq);
            if (less) lo = mid; else hi = mid;
        }
    }
    kdst[db + hi] = mk;
    pdst[db + hi] = mp;
}

// ---------------------------------------------------------------------------
// Kernel 4: final merge 2048 -> 4096 FUSED with gather/clip of sorted arrays.
// ---------------------------------------------------------------------------
__global__ __launch_bounds__(256) void mergeG_kernel(
    const unsigned int* __restrict__ ksrc,
    const unsigned short* __restrict__ psrc,
    const float* __restrict__ proposals,
    const float* __restrict__ conf,
    const float* __restrict__ clsf,
    const unsigned char* __restrict__ cv,
    float* __restrict__ boxes_s,
    float* __restrict__ conf_s,
    float* __restrict__ clsf_s,
    unsigned char* __restrict__ cv_s)
{
    const int i = blockIdx.x * 256 + threadIdx.x;   // BN threads
    const int R = 2048;
    unsigned int mk = ksrc[i]; unsigned short mp = psrc[i];
    int base = i & ~(2 * R - 1);
    bool isA = (i & R) == 0;
    int sb = base + (isA ? R : 0);
    int db = base + (i & (R - 1));
    bool teq = !isA;
    int lo = -1, hi = R;
    for (int s = 0; s < 12; ++s) {
        if (hi - lo > 1) {
            int mid = (lo + hi) >> 1;
            unsigned int sk = ksrc[sb + mid];
            bool less = (sk < mk) || (sk == mk && teq);
            if (less) lo = mid; else hi = mid;
        }
    }
    int dst = db + hi;                  // global sorted index (same batch)
    int bb  = dst >> 12;
    int src = (bb << 12) + (int)mp;
    float4 bx = *reinterpret_cast<const float4*>(proposals + (size_t)src * 4);
    float x1 = clipf(bx.x, 0.f, 602.f);
    float y1 = clipf(bx.y, 0.f, 602.f);
    float x2 = clipf(bx.z, 0.f, 602.f);
    float y2 = clipf(bx.w, 0.f, 602.f);
    *reinterpret_cast<float4*>(boxes_s + (size_t)dst * 4) =
        make_float4(x1, y1, x2, y2);
    conf_s[dst] = conf[src];
    clsf_s[dst] = clsf[src];
    cv_s[dst]   = cv[src];
}

// ---------------------------------------------------------------------------
// Kernel 5: per-(batch,class) greedy NMS, one wave/block; writes survivors'
// output rows directly (out pre-zeroed by score_kernel).
// ---------------------------------------------------------------------------
__device__ __forceinline__ void emit_row(
    const float* __restrict__ boxes_s, const float* __restrict__ conf_s,
    const float* __restrict__ clsf_s, float* __restrict__ out, int row)
{
    float4 bb = *reinterpret_cast<const float4*>(boxes_s + (size_t)row * 4);
    size_t o = (size_t)row * 6;
    out[o + 0] = bb.x; out[o + 1] = bb.y;
    out[o + 2] = bb.z; out[o + 3] = bb.w;
    out[o + 4] = conf_s[row];
    out[o + 5] = clsf_s[row];
    out[(size_t)BN_ * 6 + row] = 1.f;
}

__global__ __launch_bounds__(64) void nms_kernel(
    const float* __restrict__ boxes_s,
    const float* __restrict__ conf_s,
    const float* __restrict__ clsf_s,
    const unsigned char* __restrict__ cv_s,
    float* __restrict__ out)
{
    __shared__ unsigned short flist[N_];
    __shared__ unsigned char alive8[N_];
    const int bc = blockIdx.x;
    const int b = bc >> 6, c = bc & 63;
    const int lane = threadIdx.x;
    const float offc = (float)c * 4096.0f;          // exact in f32
    const unsigned char* cv = cv_s + (size_t)b * N_;

    // ordered ballot compaction (single wave; LDS program-ordered)
    int base = 0;
    #pragma unroll 16
    for (int it = 0; it < N_ / 64; ++it) {
        bool pred = cv[it * 64 + lane] == (unsigned char)c;
        unsigned long long m = __ballot(pred);
        if (pred)
            flist[base + __popcll(m & ((1ull << lane) - 1ull))] =
                (unsigned short)(it * 64 + lane);
        base += __popcll(m);
    }
    const int L = base;
    if (L <= 1) {
        if (lane < L)
            emit_row(boxes_s, conf_s, clsf_s, out, b * N_ + flist[lane]);
        return;
    }

    if (L <= 64) {
        bool in = lane < L;
        unsigned short myp = in ? flist[lane] : (unsigned short)0;
        float x1 = offc, y1 = offc, x2 = offc, y2 = offc, ar = 0.f;
        if (in) {
            float4 bb = *reinterpret_cast<const float4*>(
                boxes_s + ((size_t)b * N_ + myp) * 4);
            x1 = __fadd_rn(bb.x, offc); y1 = __fadd_rn(bb.y, offc);
            x2 = __fadd_rn(bb.z, offc); y2 = __fadd_rn(bb.w, offc);
            ar = __fmul_rn(fmaxf(__fsub_rn(x2, x1), 0.f),
                           fmaxf(__fsub_rn(y2, y1), 0.f));
        }
        // parallel suppression bit-matrix: no loop-carried dependency
        unsigned long long row = 0;
        for (int j = 1; j < L; ++j) {
            float jx1 = bcastf(x1, j), jy1 = bcastf(y1, j);
            float jx2 = bcastf(x2, j), jy2 = bcastf(y2, j);
            float jar = bcastf(ar, j);
            float iou = iou_rn(jx1, jy1, jx2, jy2, jar, x1, y1, x2, y2, ar);
            if (in && j > lane && iou > 0.2f) row |= 1ull << j;
        }
        // serial cascade over bits
        unsigned long long alive = (L >= 64) ? ~0ull : ((1ull << L) - 1ull);
        unsigned int rlo = (unsigned int)row, rhi = (unsigned int)(row >> 32);
        for (int k = 0; k < L - 1; ++k) {
            if ((alive >> k) & 1ull) {
                unsigned int lo = (unsigned int)__builtin_amdgcn_readlane((int)rlo, k);
                unsigned int hi = (unsigned int)__builtin_amdgcn_readlane((int)rhi, k);
                alive &= ~(((unsigned long long)hi << 32) | (unsigned long long)lo);
            }
        }
        if (in && ((alive >> lane) & 1ull))
            emit_row(boxes_s, conf_s, clsf_s, out, b * N_ + myp);
    } else if (L <= 128) {
        bool in1 = (64 + lane) < L;
        unsigned short myp0 = flist[lane];
        unsigned short myp1 = in1 ? flist[64 + lane] : (unsigned short)0;
        float ax1, ay1, ax2, ay2, aar;
        {
            float4 bb = *reinterpret_cast<const float4*>(
                boxes_s + ((size_t)b * N_ + myp0) * 4);
            ax1 = __fadd_rn(bb.x, offc); ay1 = __fadd_rn(bb.y, offc);
            ax2 = __fadd_rn(bb.z, offc); ay2 = __fadd_rn(bb.w, offc);
            aar = __fmul_rn(fmaxf(__fsub_rn(ax2, ax1), 0.f),
                            fmaxf(__fsub_rn(ay2, ay1), 0.f));
        }
        float bx1 = offc, by1 = offc, bx2 = offc, by2 = offc, bar = 0.f;
        if (in1) {
            float4 bb = *reinterpret_cast<const float4*>(
                boxes_s + ((size_t)b * N_ + myp1) * 4);
            bx1 = __fadd_rn(bb.x, offc); by1 = __fadd_rn(bb.y, offc);
            bx2 = __fadd_rn(bb.z, offc); by2 = __fadd_rn(bb.w, offc);
            bar = __fmul_rn(fmaxf(__fsub_rn(bx2, bx1), 0.f),
                            fmaxf(__fsub_rn(by2, by1), 0.f));
        }
        unsigned long long r0lo = 0, r0hi = 0, r1hi = 0;
        for (int j = 1; j < 64; ++j) {
            float jx1 = bcastf(ax1, j), jy1 = bcastf(ay1, j);
            float jx2 = bcastf(ax2, j), jy2 = bcastf(ay2, j);
            float jar = bcastf(aar, j);
            float i0 = iou_rn(jx1, jy1, jx2, jy2, jar, ax1, ay1, ax2, ay2, aar);
            if (j > lane && i0 > 0.2f) r0lo |= 1ull << j;
        }
        const int Lh = L - 64;
        for (int jm = 0; jm < Lh; ++jm) {
            float jx1 = bcastf(bx1, jm), jy1 = bcastf(by1, jm);
            float jx2 = bcastf(bx2, jm), jy2 = bcastf(by2, jm);
            float jar = bcastf(bar, jm);
            float i0 = iou_rn(jx1, jy1, jx2, jy2, jar, ax1, ay1, ax2, ay2, aar);
            if (i0 > 0.2f) r0hi |= 1ull << jm;      // 64+jm > lane always
            float i1 = iou_rn(jx1, jy1, jx2, jy2, jar, bx1, by1, bx2, by2, bar);
            if (in1 && jm > lane && i1 > 0.2f) r1hi |= 1ull << jm;
        }
        unsigned long long alo = ~0ull;
        unsigned long long ahi = (Lh >= 64) ? ~0ull : ((1ull << Lh) - 1ull);
        for (int k = 0; k < 64; ++k) {
            if ((alo >> k) & 1ull) {
                alo &= ~bcast64(r0lo, k);
                ahi &= ~bcast64(r0hi, k);
            }
        }
        for (int k = 0; k < Lh - 1; ++k) {
            if ((ahi >> k) & 1ull) ahi &= ~bcast64(r1hi, k);
        }
        if ((alo >> lane) & 1ull)
            emit_row(boxes_s, conf_s, clsf_s, out, b * N_ + myp0);
        if (in1 && ((ahi >> lane) & 1ull))
            emit_row(boxes_s, conf_s, clsf_s, out, b * N_ + myp1);
    } else {
        // generic fallback (not expected with this data)
        for (int j = lane; j < L; j += 64) alive8[j] = 1;
        for (int k = 0; k < L - 1; ++k) {
            if (!alive8[k]) continue;
            float4 kb = *reinterpret_cast<const float4*>(
                boxes_s + ((size_t)b * N_ + flist[k]) * 4);
            float kx1 = __fadd_rn(kb.x, offc), ky1 = __fadd_rn(kb.y, offc);
            float kx2 = __fadd_rn(kb.z, offc), ky2 = __fadd_rn(kb.w, offc);
            float kar = __fmul_rn(fmaxf(__fsub_rn(kx2, kx1), 0.f),
                                  fmaxf(__fsub_rn(ky2, ky1), 0.f));
            for (int j = k + 1 + lane; j < L; j += 64) {
                if (!alive8[j]) continue;
                float4 bb = *reinterpret_cast<const float4*>(
                    boxes_s + ((size_t)b * N_ + flist[j]) * 4);
                float a1 = __fadd_rn(bb.x, offc), b1 = __fadd_rn(bb.y, offc);
                float a2 = __fadd_rn(bb.z, offc), b2 = __fadd_rn(bb.w, offc);
                float arj = __fmul_rn(fmaxf(__fsub_rn(a2, a1), 0.f),
                                      fmaxf(__fsub_rn(b2, b1), 0.f));
                float iou = iou_rn(kx1, ky1, kx2, ky2, kar, a1, b1, a2, b2, arj);
                if (iou > 0.2f) alive8[j] = 0;
            }
        }
        for (int j = lane; j < L; j += 64)
            if (alive8[j])
                emit_row(boxes_s, conf_s, clsf_s, out, b * N_ + flist[j]);
    }
}

// ---------------------------------------------------------------------------
extern "C" void kernel_launch(void* const* d_in, const int* in_sizes, int n_in,
                              void* d_out, int out_size, void* d_ws, size_t ws_size,
                              hipStream_t stream) {
    (void)in_sizes; (void)n_in; (void)out_size; (void)ws_size;
    const float* proposals = (const float*)d_in[0];
    const float* preds     = (const float*)d_in[1];
    const float* scores    = (const float*)d_in[2];
    float* out = (float*)d_out;

    uint8_t* w = (uint8_t*)d_ws;
    unsigned int* key32    = (unsigned int*)(w);                      // 0..4
    float* conf            = (float*)(w + (size_t)BN_ * 4);           // 4..8
    float* clsf            = (float*)(w + (size_t)BN_ * 8);           // 8..12
    unsigned int* runkey   = (unsigned int*)(w + (size_t)BN_ * 12);   // 12..16
    unsigned int* mk2      = (unsigned int*)(w + (size_t)BN_ * 16);   // 16..20
    float* boxes_s         = (float*)(w + (size_t)BN_ * 20);          // 20..36
    float* conf_s          = (float*)(w + (size_t)BN_ * 36);          // 36..40
    float* clsf_s          = (float*)(w + (size_t)BN_ * 40);          // 40..44
    unsigned short* runpay = (unsigned short*)(w + (size_t)BN_ * 44); // 44..46
    unsigned short* mp2    = (unsigned short*)(w + (size_t)BN_ * 46); // 46..48
    unsigned char* cv      = w + (size_t)BN_ * 48;                    // 48..49
    unsigned char* cv_s    = w + (size_t)BN_ * 49;                    // 49..50

    score_kernel<<<(BN_ * 16) / 256, 256, 0, stream>>>(
        proposals, preds, scores, key32, conf, clsf, cv, out);
    sortA_kernel<<<64, 256, 0, stream>>>(key32, runkey, runpay);
    merge1_kernel<<<BN_ / 256, 256, 0, stream>>>(runkey, runpay, mk2, mp2);
    mergeG_kernel<<<BN_ / 256, 256, 0, stream>>>(
        mk2, mp2, proposals, conf, clsf, cv,
        boxes_s, conf_s, clsf_s, cv_s);
    nms_kernel<<<B_ * C_, 64, 0, stream>>>(
        boxes_s, conf_s, clsf_s, cv_s, out);
}